// Round 2
// baseline (271.775 us; speedup 1.0000x reference)
//
#include <hip/hip_runtime.h>
#include <hip/hip_fp16.h>

#define EPS 1e-8f

typedef float v2f __attribute__((ext_vector_type(2)));
typedef int   v4i __attribute__((ext_vector_type(4)));
typedef unsigned v2u __attribute__((ext_vector_type(2)));

__device__ __forceinline__ float dot16_fp8(uint4 A, uint4 B) {
    const unsigned* pa = (const unsigned*)&A;
    const unsigned* pb = (const unsigned*)&B;
    float acc = 0.0f;
#pragma unroll
    for (int i = 0; i < 4; ++i) {
        v2f a01 = __builtin_amdgcn_cvt_pk_f32_fp8((int)pa[i], false);
        v2f a23 = __builtin_amdgcn_cvt_pk_f32_fp8((int)pa[i], true);
        v2f b01 = __builtin_amdgcn_cvt_pk_f32_fp8((int)pb[i], false);
        v2f b23 = __builtin_amdgcn_cvt_pk_f32_fp8((int)pb[i], true);
        acc += a01[0] * b01[0] + a01[1] * b01[1]
             + a23[0] * b23[0] + a23[1] * b23[1];
    }
    return acc;
}

__device__ __forceinline__ float sigmoidf_(float x) {
    return 1.0f / (1.0f + __expf(-x));
}

// Kernel 0: convert both f32 emb tables to fp8 e4m3 (OCP) in workspace
// (shrinks gather tables to 1.6 MB each -> L2-resident), and zero row_sum
// (ws is poisoned between runs; atomics need a clean accumulator).
__global__ __launch_bounds__(256) void convert_fp8_kernel(
    const float4* __restrict__ emb1, const float4* __restrict__ emb2,
    unsigned* __restrict__ q1, unsigned* __restrict__ q2, int n4,
    float* __restrict__ row_sum, int n_nodes)
{
    int i = blockIdx.x * blockDim.x + threadIdx.x;
    if (i < n4) {
        float4 a = emb1[i];
        float4 b = emb2[i];
        int pa = __builtin_amdgcn_cvt_pk_fp8_f32(a.x, a.y, 0, false);
        pa     = __builtin_amdgcn_cvt_pk_fp8_f32(a.z, a.w, pa, true);
        int pb = __builtin_amdgcn_cvt_pk_fp8_f32(b.x, b.y, 0, false);
        pb     = __builtin_amdgcn_cvt_pk_fp8_f32(b.z, b.w, pb, true);
        q1[i] = (unsigned)pa;
        q2[i] = (unsigned)pb;
    }
    int nzq = n_nodes >> 2;   // zero row_sum with float4 stores
    if (i < nzq) {
        float4 z; z.x = 0.f; z.y = 0.f; z.z = 0.f; z.w = 0.f;
        ((float4*)row_sum)[i] = z;
    }
    if (i == 0) {
        for (int r = nzq << 2; r < n_nodes; ++r) row_sum[r] = 0.f;
    }
}

// Kernel 1: gather + dot + sigmoid + store w (f16) + fire-and-forget
// global atomicAdd into row_sum. Replaces the 8x-partitioned LDS histogram
// (which re-read the whole edge stream per partition: ~160 MB) with ~45 MB
// of traffic. atomicAdd result is unused -> no-return global_atomic_add_f32,
// waves never stall on it. 4 edges/thread: int4 index loads, 8 independent
// L2-resident 16B gathers in flight.
__global__ __launch_bounds__(256) void gather_dot_atomic_kernel(
    const int* __restrict__ src, const int* __restrict__ dst,
    const uint4* __restrict__ q1, const uint4* __restrict__ q2,
    __half* __restrict__ w, float* __restrict__ row_sum, int n_edges)
{
    int t = blockIdx.x * blockDim.x + threadIdx.x;
    int nq = n_edges >> 2;
    if (t < nq) {
        v4i s = __builtin_nontemporal_load((const v4i*)src + t);
        v4i d = __builtin_nontemporal_load((const v4i*)dst + t);
        uint4 A0 = q1[s.x];
        uint4 A1 = q1[s.y];
        uint4 A2 = q1[s.z];
        uint4 A3 = q1[s.w];
        uint4 B0 = q2[d.x];
        uint4 B1 = q2[d.y];
        uint4 B2 = q2[d.z];
        uint4 B3 = q2[d.w];
        float w0 = sigmoidf_(dot16_fp8(A0, B0));
        float w1 = sigmoidf_(dot16_fp8(A1, B1));
        float w2 = sigmoidf_(dot16_fp8(A2, B2));
        float w3 = sigmoidf_(dot16_fp8(A3, B3));
        __half2 h01 = __floats2half2_rn(w0, w1);
        __half2 h23 = __floats2half2_rn(w2, w3);
        v2u pack;
        pack.x = *(unsigned*)&h01;
        pack.y = *(unsigned*)&h23;
        __builtin_nontemporal_store(pack, (v2u*)w + t);
        atomicAdd(&row_sum[s.x], w0);
        atomicAdd(&row_sum[s.y], w1);
        atomicAdd(&row_sum[s.z], w2);
        atomicAdd(&row_sum[s.w], w3);
    }
    if (t == 0) {   // scalar tail (n_edges % 4)
        for (int e = nq << 2; e < n_edges; ++e) {
            int ss = src[e];
            int dd = dst[e];
            float wv = sigmoidf_(dot16_fp8(q1[ss], q2[dd]));
            w[e] = __float2half(wv);
            atomicAdd(&row_sum[ss], wv);
        }
    }
}

// Kernel 2: normalize. 8 edges/thread -- 8 independent L2-resident gathers
// in flight per thread.
__global__ __launch_bounds__(256) void edge_norm_kernel(
    const int* __restrict__ src, const __half* __restrict__ w,
    const float* __restrict__ row_sum, float* __restrict__ out, int n_edges)
{
    int t = blockIdx.x * blockDim.x + threadIdx.x;
    int e0 = t * 8;
    if (e0 + 7 < n_edges) {
        int4 sa = ((const int4*)src)[t * 2];
        int4 sb = ((const int4*)src)[t * 2 + 1];
        uint2 wra = ((const uint2*)w)[t * 2];
        uint2 wrb = ((const uint2*)w)[t * 2 + 1];
        float r0 = row_sum[sa.x];
        float r1 = row_sum[sa.y];
        float r2 = row_sum[sa.z];
        float r3 = row_sum[sa.w];
        float r4 = row_sum[sb.x];
        float r5 = row_sum[sb.y];
        float r6 = row_sum[sb.z];
        float r7 = row_sum[sb.w];
        const __half2* wha = (const __half2*)&wra;
        const __half2* whb = (const __half2*)&wrb;
        float2 w01 = __half22float2(wha[0]);
        float2 w23 = __half22float2(wha[1]);
        float2 w45 = __half22float2(whb[0]);
        float2 w67 = __half22float2(whb[1]);
        float4 oa, ob;
        oa.x = w01.x / (r0 + EPS);
        oa.y = w01.y / (r1 + EPS);
        oa.z = w23.x / (r2 + EPS);
        oa.w = w23.y / (r3 + EPS);
        ob.x = w45.x / (r4 + EPS);
        ob.y = w45.y / (r5 + EPS);
        ob.z = w67.x / (r6 + EPS);
        ob.w = w67.y / (r7 + EPS);
        ((float4*)out)[t * 2] = oa;
        ((float4*)out)[t * 2 + 1] = ob;
    } else if (e0 < n_edges) {
        for (int e = e0; e < n_edges; ++e) {
            out[e] = __half2float(w[e]) / (row_sum[src[e]] + EPS);
        }
    }
}

extern "C" void kernel_launch(void* const* d_in, const int* in_sizes, int n_in,
                              void* d_out, int out_size, void* d_ws, size_t ws_size,
                              hipStream_t stream) {
    const int*   src  = (const int*)d_in[0];
    const int*   dst  = (const int*)d_in[1];
    const float* emb1 = (const float*)d_in[2];
    const float* emb2 = (const float*)d_in[3];
    float* out = (float*)d_out;

    int n_edges = in_sizes[0];
    int n_emb   = in_sizes[2];          // N_NODES * 16 floats
    int n_nodes = n_emb / 16;

    // ws layout (16B-aligned chunks), total ~10 MB:
    //   row_sum : n_nodes f32       (400 KB)
    //   w       : n_edges f16       (6.4 MB)
    //   q1, q2  : n_emb fp8         (1.6 MB each)
    char* base = (char*)d_ws;
    float*   row_sum = (float*)base;
    size_t off = ((size_t)n_nodes * sizeof(float) + 15) & ~(size_t)15;
    __half*  w = (__half*)(base + off);
    off += ((size_t)n_edges * sizeof(__half) + 15) & ~(size_t)15;
    unsigned* q1 = (unsigned*)(base + off);
    off += ((size_t)n_emb + 15) & ~(size_t)15;
    unsigned* q2 = (unsigned*)(base + off);

    int block = 256;
    int n4 = n_emb / 4;
    convert_fp8_kernel<<<(n4 + block - 1) / block, block, 0, stream>>>(
        (const float4*)emb1, (const float4*)emb2, q1, q2, n4, row_sum, n_nodes);

    int nq = n_edges >> 2;
    int gblocks = (nq + block - 1) / block;
    if (gblocks < 1) gblocks = 1;
    gather_dot_atomic_kernel<<<gblocks, block, 0, stream>>>(
        src, dst, (const uint4*)q1, (const uint4*)q2, w, row_sum, n_edges);

    int n_oct = (n_edges + 7) / 8;
    edge_norm_kernel<<<(n_oct + block - 1) / block, block, 0, stream>>>(
        src, w, row_sum, out, n_edges);
}

// Round 3
// 162.087 us; speedup vs baseline: 1.6767x; 1.6767x over previous
//
#include <hip/hip_runtime.h>
#include <hip/hip_fp16.h>

#define EPS 1e-8f
#define HBLK 1024      // hist block: 16 waves for latency hiding

typedef float    v2f __attribute__((ext_vector_type(2)));
typedef int      v4i __attribute__((ext_vector_type(4)));
typedef unsigned v4u __attribute__((ext_vector_type(4)));

__device__ __forceinline__ float dot16_fp8(uint4 A, uint4 B) {
    const unsigned* pa = (const unsigned*)&A;
    const unsigned* pb = (const unsigned*)&B;
    float acc = 0.0f;
#pragma unroll
    for (int i = 0; i < 4; ++i) {
        v2f a01 = __builtin_amdgcn_cvt_pk_f32_fp8((int)pa[i], false);
        v2f a23 = __builtin_amdgcn_cvt_pk_f32_fp8((int)pa[i], true);
        v2f b01 = __builtin_amdgcn_cvt_pk_f32_fp8((int)pb[i], false);
        v2f b23 = __builtin_amdgcn_cvt_pk_f32_fp8((int)pb[i], true);
        acc += a01[0] * b01[0] + a01[1] * b01[1]
             + a23[0] * b23[0] + a23[1] * b23[1];
    }
    return acc;
}

__device__ __forceinline__ float sigmoidf_(float x) {
    return 1.0f / (1.0f + __expf(-x));
}

// Kernel 0: convert both f32 emb tables to fp8 e4m3 (OCP) in workspace
// (shrinks gather tables to 1.6 MB each -> L2-resident).
__global__ __launch_bounds__(256) void convert_fp8_kernel(
    const float4* __restrict__ emb1, const float4* __restrict__ emb2,
    unsigned* __restrict__ q1, unsigned* __restrict__ q2, int n4)
{
    int i = blockIdx.x * blockDim.x + threadIdx.x;
    if (i >= n4) return;
    float4 a = emb1[i];
    float4 b = emb2[i];
    int pa = __builtin_amdgcn_cvt_pk_fp8_f32(a.x, a.y, 0, false);
    pa     = __builtin_amdgcn_cvt_pk_fp8_f32(a.z, a.w, pa, true);
    int pb = __builtin_amdgcn_cvt_pk_fp8_f32(b.x, b.y, 0, false);
    pb     = __builtin_amdgcn_cvt_pk_fp8_f32(b.z, b.w, pb, true);
    q1[i] = (unsigned)pa;
    q2[i] = (unsigned)pb;
}

// Kernel 1: gather + dot + sigmoid, emit ONE u32 per edge:
//   pk = (src << 15) | round(w * 32767)
// src < 2^17, w in (0,1) -> 15-bit fixed point (abs err 1.5e-5, better than
// f16). This single 12.8 MB stream (L3-resident) feeds BOTH the histogram
// passes (4 B/edge instead of 6) and edge_norm (no separate src/w re-read).
// NO global atomics (R1 falsified: 3.2M scattered f32 atomics = 106 MB of
// 32B memory-side RMW, 172 us).
__global__ __launch_bounds__(256) void gather_pack_kernel(
    const int* __restrict__ src, const int* __restrict__ dst,
    const uint4* __restrict__ q1, const uint4* __restrict__ q2,
    unsigned* __restrict__ packed, int n_edges)
{
    int t = blockIdx.x * blockDim.x + threadIdx.x;
    int nq = n_edges >> 2;
    if (t < nq) {
        v4i s = __builtin_nontemporal_load((const v4i*)src + t);
        v4i d = __builtin_nontemporal_load((const v4i*)dst + t);
        uint4 A0 = q1[s.x];
        uint4 A1 = q1[s.y];
        uint4 A2 = q1[s.z];
        uint4 A3 = q1[s.w];
        uint4 B0 = q2[d.x];
        uint4 B1 = q2[d.y];
        uint4 B2 = q2[d.z];
        uint4 B3 = q2[d.w];
        float w0 = sigmoidf_(dot16_fp8(A0, B0));
        float w1 = sigmoidf_(dot16_fp8(A1, B1));
        float w2 = sigmoidf_(dot16_fp8(A2, B2));
        float w3 = sigmoidf_(dot16_fp8(A3, B3));
        v4u pk;
        pk.x = ((unsigned)s.x << 15) | __float2uint_rn(w0 * 32767.0f);
        pk.y = ((unsigned)s.y << 15) | __float2uint_rn(w1 * 32767.0f);
        pk.z = ((unsigned)s.z << 15) | __float2uint_rn(w2 * 32767.0f);
        pk.w = ((unsigned)s.w << 15) | __float2uint_rn(w3 * 32767.0f);
        // regular store (not nontemporal): keep it cache-resident for hist
        ((v4u*)packed)[t] = pk;
    }
    if (t == 0) {   // scalar tail (n_edges % 4)
        for (int e = nq << 2; e < n_edges; ++e) {
            int ss = src[e];
            float wv = sigmoidf_(dot16_fp8(q1[ss], q2[dst[e]]));
            packed[e] = ((unsigned)ss << 15) | __float2uint_rn(wv * 32767.0f);
        }
    }
}

// Kernel 2: LDS-privatized partitioned histogram over the packed stream.
// PART/NP/GE are runtime (100 KB dynamic-LDS NP=4 path, or 64 KB NP=7
// fallback). grid = GE*NP, 1 block/CU at 100 KB.
__global__ __launch_bounds__(HBLK) void hist_kernel(
    const unsigned* __restrict__ packed, __half* __restrict__ partial,
    int n_edges, int n_nodes, int PART, int NP, int GE)
{
    extern __shared__ float lds[];
    int bid = blockIdx.x;
    int c = bid / NP;       // edge chunk
    int p = bid % NP;       // node partition
    int tid = threadIdx.x;
    int base = p * PART;

    for (int i = tid; i < PART; i += HBLK) lds[i] = 0.0f;
    __syncthreads();

    int nq = n_edges >> 2;
    int per = (nq + GE - 1) / GE;
    int q0 = c * per;
    int q1e = min(q0 + per, nq);

    const v4u* p4 = (const v4u*)packed;
    const float inv = 1.0f / 32767.0f;
    for (int q = q0 + tid; q < q1e; q += HBLK) {
        v4u pk = p4[q];
        unsigned i0 = (pk.x >> 15) - base;
        unsigned i1 = (pk.y >> 15) - base;
        unsigned i2 = (pk.z >> 15) - base;
        unsigned i3 = (pk.w >> 15) - base;
        if (i0 < (unsigned)PART) atomicAdd(&lds[i0], (float)(pk.x & 32767u) * inv);
        if (i1 < (unsigned)PART) atomicAdd(&lds[i1], (float)(pk.y & 32767u) * inv);
        if (i2 < (unsigned)PART) atomicAdd(&lds[i2], (float)(pk.z & 32767u) * inv);
        if (i3 < (unsigned)PART) atomicAdd(&lds[i3], (float)(pk.w & 32767u) * inv);
    }
    if (c == GE - 1) {
        for (int e = (nq << 2) + tid; e < n_edges; e += HBLK) {
            unsigned pk = packed[e];
            unsigned i = (pk >> 15) - base;
            if (i < (unsigned)PART) atomicAdd(&lds[i], (float)(pk & 32767u) * inv);
        }
    }
    __syncthreads();

    int lim = min(PART, n_nodes - base);
    size_t pb = (size_t)c * n_nodes + base;
    for (int i = tid; i < lim; i += HBLK)
        partial[pb + i] = __float2half(lds[i]);
}

// Kernel 3: fold partials -> row_sum (fully overwrites; no memset needed).
__global__ __launch_bounds__(256) void fold_kernel(
    const __half* __restrict__ partial, float* __restrict__ row_sum,
    int n_nodes, int GE)
{
    int n = blockIdx.x * blockDim.x + threadIdx.x;
    if (n >= n_nodes) return;
    float acc = 0.0f;
#pragma unroll 4
    for (int c = 0; c < GE; ++c)
        acc += __half2float(partial[(size_t)c * n_nodes + n]);
    row_sum[n] = acc;
}

// Kernel 4: normalize. 8 edges/thread from the packed stream; 8 independent
// L2-resident row_sum gathers in flight per thread.
__global__ __launch_bounds__(256) void edge_norm_kernel(
    const unsigned* __restrict__ packed, const float* __restrict__ row_sum,
    float* __restrict__ out, int n_edges)
{
    int t = blockIdx.x * blockDim.x + threadIdx.x;
    int e0 = t * 8;
    const float inv = 1.0f / 32767.0f;
    if (e0 + 7 < n_edges) {
        v4u pa = ((const v4u*)packed)[t * 2];
        v4u pb = ((const v4u*)packed)[t * 2 + 1];
        float r0 = row_sum[pa.x >> 15];
        float r1 = row_sum[pa.y >> 15];
        float r2 = row_sum[pa.z >> 15];
        float r3 = row_sum[pa.w >> 15];
        float r4 = row_sum[pb.x >> 15];
        float r5 = row_sum[pb.y >> 15];
        float r6 = row_sum[pb.z >> 15];
        float r7 = row_sum[pb.w >> 15];
        float4 oa, ob;
        oa.x = (float)(pa.x & 32767u) * inv / (r0 + EPS);
        oa.y = (float)(pa.y & 32767u) * inv / (r1 + EPS);
        oa.z = (float)(pa.z & 32767u) * inv / (r2 + EPS);
        oa.w = (float)(pa.w & 32767u) * inv / (r3 + EPS);
        ob.x = (float)(pb.x & 32767u) * inv / (r4 + EPS);
        ob.y = (float)(pb.y & 32767u) * inv / (r5 + EPS);
        ob.z = (float)(pb.z & 32767u) * inv / (r6 + EPS);
        ob.w = (float)(pb.w & 32767u) * inv / (r7 + EPS);
        ((float4*)out)[t * 2] = oa;
        ((float4*)out)[t * 2 + 1] = ob;
    } else if (e0 < n_edges) {
        for (int e = e0; e < n_edges; ++e) {
            unsigned pk = packed[e];
            out[e] = (float)(pk & 32767u) * inv / (row_sum[pk >> 15] + EPS);
        }
    }
}

extern "C" void kernel_launch(void* const* d_in, const int* in_sizes, int n_in,
                              void* d_out, int out_size, void* d_ws, size_t ws_size,
                              hipStream_t stream) {
    const int*   src  = (const int*)d_in[0];
    const int*   dst  = (const int*)d_in[1];
    const float* emb1 = (const float*)d_in[2];
    const float* emb2 = (const float*)d_in[3];
    float* out = (float*)d_out;

    int n_edges = in_sizes[0];
    int n_emb   = in_sizes[2];          // N_NODES * 16 floats
    int n_nodes = n_emb / 16;

    // Pick hist geometry once: 100 KB dynamic LDS (NP=4) if allowed,
    // else 64 KB-safe NP=7. hipFuncSetAttribute is host-side, capture-safe.
    static int use_big = -1;
    if (use_big < 0) {
        hipError_t e = hipFuncSetAttribute(
            reinterpret_cast<const void*>(hist_kernel),
            hipFuncAttributeMaxDynamicSharedMemorySize, 25000 * 4);
        use_big = (e == hipSuccess) ? 1 : 0;
    }
    int PART = use_big ? 25000 : 16000;
    int NP   = use_big ? 4     : 7;
    int GE   = use_big ? 64    : 37;    // ~256 blocks either way
    size_t lds_bytes = (size_t)PART * sizeof(float);

    // ws layout (16B-aligned chunks), total ~29 MB:
    //   row_sum : n_nodes f32            (400 KB)
    //   packed  : n_edges u32            (12.8 MB)
    //   q1, q2  : n_emb fp8              (1.6 MB each)
    //   partial : GE_max(=64)*n_nodes f16 (12.8 MB)
    char* base = (char*)d_ws;
    float* row_sum = (float*)base;
    size_t off = ((size_t)n_nodes * sizeof(float) + 15) & ~(size_t)15;
    unsigned* packed = (unsigned*)(base + off);
    off += ((size_t)n_edges * sizeof(unsigned) + 15) & ~(size_t)15;
    unsigned* q1 = (unsigned*)(base + off);
    off += ((size_t)n_emb + 15) & ~(size_t)15;
    unsigned* q2 = (unsigned*)(base + off);
    off += ((size_t)n_emb + 15) & ~(size_t)15;
    __half* partial = (__half*)(base + off);

    int block = 256;
    int n4 = n_emb / 4;
    convert_fp8_kernel<<<(n4 + block - 1) / block, block, 0, stream>>>(
        (const float4*)emb1, (const float4*)emb2, q1, q2, n4);

    int nq = n_edges >> 2;
    int gblocks = (nq + block - 1) / block;
    if (gblocks < 1) gblocks = 1;
    gather_pack_kernel<<<gblocks, block, 0, stream>>>(
        src, dst, (const uint4*)q1, (const uint4*)q2, packed, n_edges);

    hist_kernel<<<GE * NP, HBLK, lds_bytes, stream>>>(
        packed, partial, n_edges, n_nodes, PART, NP, GE);

    fold_kernel<<<(n_nodes + block - 1) / block, block, 0, stream>>>(
        partial, row_sum, n_nodes, GE);

    int n_oct = (n_edges + 7) / 8;
    edge_norm_kernel<<<(n_oct + block - 1) / block, block, 0, stream>>>(
        packed, row_sum, out, n_edges);
}